// Round 4
// baseline (192.934 us; speedup 1.0000x reference)
//
#include <hip/hip_runtime.h>
#include <stdint.h>

#define BROWS 16384
#define DDIM  512
#define EEXP  16
#define HDIM  256
#define LDIM  64
#define BM    128

typedef __bf16  bf16x8  __attribute__((ext_vector_type(8)));
typedef float   floatx4 __attribute__((ext_vector_type(4)));
typedef ushort  ushort8 __attribute__((ext_vector_type(8)));
typedef unsigned int u32;

__device__ __forceinline__ ushort f2bf(float f) {
    uint32_t u = __builtin_bit_cast(uint32_t, f);
    u += 0x7fffu + ((u >> 16) & 1u);   // RNE
    return (ushort)(u >> 16);
}

// tanh(x) = 1 - 2/(exp2(2x*log2e)+1); saturates correctly, rel err ~1e-6.
__device__ __forceinline__ float fast_tanh(float x) {
    float e = __builtin_amdgcn_exp2f(x * 2.8853900817779268f);
    return 1.0f - 2.0f * __builtin_amdgcn_rcpf(e + 1.0f);
}

__device__ __forceinline__ void gl_lds16(const void* g, void* l) {
    __builtin_amdgcn_global_load_lds(
        (const __attribute__((address_space(1))) u32*)g,
        (__attribute__((address_space(3))) u32*)l, 16, 0, 0);
}

// ---------------------------------------------------------------------------
// MERGED kernel. Blocks 0..511: gating (f32 math unchanged) + fused x->bf16
// swizzled cvt + INLINE zero-fill of inactive out slots + direct atomic
// rowlist build. Blocks 512..2815: W1/W2 transpose+cvt.
// ---------------------------------------------------------------------------
__global__ __launch_bounds__(256) void gate_aux_kernel(
    const float* __restrict__ x,      // [B][D]
    const float* __restrict__ noise,  // [B][E]
    const float* __restrict__ wg,     // [D][E]
    const float* __restrict__ wn,     // [D][E]
    const float* __restrict__ W1,     // [E][D][H]
    const float* __restrict__ W2,     // [E][H][L]
    float* __restrict__ gates,        // [B][E]
    ushort* __restrict__ xbf,         // [B][D] bf16 swizzled
    ushort* __restrict__ W1T,         // [E][H][D] bf16 swizzled
    ushort* __restrict__ W2T,         // [E][L][H] bf16 linear
    u32* __restrict__ cnt,            // [E] (pre-zeroed)
    u32* __restrict__ rowlist,        // [E][B] unsorted-compact
    float* __restrict__ out)          // [B][E][L]
{
    if (blockIdx.x >= 512) {
        // ---- transpose path ----
        __shared__ float tile[32][33];
        int b = blockIdx.x - 512;
        const float* src; ushort* dst; int R, C, c0, r0, swz, ei;
        if (b < 2048) {
            ei = b >> 7; int rem = b & 127;
            c0 = (rem & 7) * 32; r0 = (rem >> 3) * 32;
            R = DDIM; C = HDIM; swz = 1;
            src = W1; dst = W1T;
        } else {
            b -= 2048;
            ei = b >> 4; int rem = b & 15;
            c0 = (rem & 1) * 32; r0 = (rem >> 1) * 32;
            R = HDIM; C = LDIM; swz = 0;
            src = W2; dst = W2T;
        }
        const int tx = threadIdx.x & 31, ty = threadIdx.x >> 5;
        const float* s = src + (size_t)ei * R * C;
        ushort* d = dst + (size_t)ei * R * C;

        #pragma unroll
        for (int i = 0; i < 4; ++i) {
            int rr = ty + i * 8;
            tile[rr][tx] = s[(size_t)(r0 + rr) * C + c0 + tx];
        }
        __syncthreads();
        #pragma unroll
        for (int i = 0; i < 4; ++i) {
            int cc = ty + i * 8;
            int h = c0 + cc;
            int col = r0 + tx;
            int col2 = col;
            if (swz) {
                int g = (col >> 3) & 7;
                col2 = (col & ~63) | ((g ^ (h & 7)) << 3) | (col & 7);
            }
            d[(size_t)h * R + col2] = f2bf(tile[tx][cc]);
        }
        return;
    }

    // ---- gating path ----
    __shared__ __align__(16) float xs[32 * 132];    // 16.5 KB
    __shared__ __align__(16) float wTg[16 * 132];   // 8.25 KB
    __shared__ __align__(16) float wTn[16 * 132];   // 8.25 KB
    __shared__ u32 lcnt[16];
    __shared__ u32 lbase[16];
    __shared__ ushort lrows[16 * 32];

    const int t    = threadIdx.x;
    const int blk  = blockIdx.x;
    const int row0 = blk * 32;
    const int og   = t & 15, rg = t >> 4;

    if (t < 16) lcnt[t] = 0;

    floatx4 accg4[2] = {}, accn4[2] = {};

    for (int ch = 0; ch < 4; ++ch) {
        const int k0 = ch * 128;
        __syncthreads();
        {   // stage xs[32][128] + fused bf16 swizzled writeback
            int r = t >> 3, c = (t & 7) * 16;
            const float* src = &x[(size_t)(row0 + r) * DDIM + k0 + c];
            float4 f[4];
            #pragma unroll
            for (int i = 0; i < 4; ++i)
                f[i] = reinterpret_cast<const float4*>(src)[i];
            float* dst = &xs[r * 132 + c];
            #pragma unroll
            for (int i = 0; i < 4; ++i)
                reinterpret_cast<float4*>(dst)[i] = f[i];

            const int row = row0 + r;
            const int sw  = r & 7;
            #pragma unroll
            for (int i = 0; i < 2; ++i) {
                int cb = k0 + c + i * 8;
                int kb = cb >> 6;
                int g  = (cb >> 3) & 7;
                int gp = g ^ sw;
                float4 a = f[i * 2], b = f[i * 2 + 1];
                ushort8 t8;
                t8[0]=f2bf(a.x); t8[1]=f2bf(a.y); t8[2]=f2bf(a.z); t8[3]=f2bf(a.w);
                t8[4]=f2bf(b.x); t8[5]=f2bf(b.y); t8[6]=f2bf(b.z); t8[7]=f2bf(b.w);
                *reinterpret_cast<ushort8*>(&xbf[(size_t)row * DDIM + kb * 64 + gp * 8]) = t8;
            }
        }
        {   // stage wTg/wTn transposed (pad 132 -> conflict-free reads)
            int d = t >> 1, e0 = (t & 1) * 8;
            float4 a0 = *reinterpret_cast<const float4*>(&wg[(size_t)(k0 + d) * EEXP + e0]);
            float4 a1 = *reinterpret_cast<const float4*>(&wg[(size_t)(k0 + d) * EEXP + e0 + 4]);
            float4 b0 = *reinterpret_cast<const float4*>(&wn[(size_t)(k0 + d) * EEXP + e0]);
            float4 b1 = *reinterpret_cast<const float4*>(&wn[(size_t)(k0 + d) * EEXP + e0 + 4]);
            wTg[(e0+0)*132+d]=a0.x; wTg[(e0+1)*132+d]=a0.y; wTg[(e0+2)*132+d]=a0.z; wTg[(e0+3)*132+d]=a0.w;
            wTg[(e0+4)*132+d]=a1.x; wTg[(e0+5)*132+d]=a1.y; wTg[(e0+6)*132+d]=a1.z; wTg[(e0+7)*132+d]=a1.w;
            wTn[(e0+0)*132+d]=b0.x; wTn[(e0+1)*132+d]=b0.y; wTn[(e0+2)*132+d]=b0.z; wTn[(e0+3)*132+d]=b0.w;
            wTn[(e0+4)*132+d]=b1.x; wTn[(e0+5)*132+d]=b1.y; wTn[(e0+6)*132+d]=b1.z; wTn[(e0+7)*132+d]=b1.w;
        }
        __syncthreads();

        #pragma unroll 8
        for (int d4 = 0; d4 < 32; ++d4) {
            floatx4 wgv = *reinterpret_cast<const floatx4*>(&wTg[og * 132 + d4 * 4]);
            floatx4 wnv = *reinterpret_cast<const floatx4*>(&wTn[og * 132 + d4 * 4]);
            #pragma unroll
            for (int rr = 0; rr < 2; ++rr) {
                floatx4 xv = *reinterpret_cast<const floatx4*>(&xs[(rg * 2 + rr) * 132 + d4 * 4]);
                accg4[rr] += xv * wgv;
                accn4[rr] += xv * wnv;
            }
        }
    }

    #pragma unroll
    for (int rr = 0; rr < 2; ++rr) {
        const int row = row0 + rg * 2 + rr;
        float accg = accg4[rr][0] + accg4[rr][1] + accg4[rr][2] + accg4[rr][3];
        float accn = accn4[rr][0] + accn4[rr][1] + accn4[rr][2] + accn4[rr][3];

        // keep libcall-precision softplus: gate threshold flips are the risk
        float sp = fmaxf(accn, 0.f) + log1pf(expf(-fabsf(accn)));
        float stddev = sp + 0.01f;
        float nz = noise[(size_t)row * EEXP + og];
        float z = accg + nz * stddev;

        float m = z;
        #pragma unroll
        for (int mask = 8; mask >= 1; mask >>= 1)
            m = fmaxf(m, __shfl_xor(m, mask, 16));
        float ez = expf(z - m);
        float s = ez;
        #pragma unroll
        for (int mask = 8; mask >= 1; mask >>= 1)
            s += __shfl_xor(s, mask, 16);
        float logit = ez / s;

        float lsum = logit;
        #pragma unroll
        for (int mask = 8; mask >= 1; mask >>= 1)
            lsum += __shfl_xor(lsum, mask, 16);
        float mean = lsum * (1.0f / 16.0f) - 1e-8f;

        float gate = (logit >= mean) ? logit : 0.0f;
        float denom = gate;
        #pragma unroll
        for (int mask = 8; mask >= 1; mask >>= 1)
            denom += __shfl_xor(denom, mask, 16);

        gates[(size_t)row * EEXP + og] = gate / denom;

        if (gate > 0.0f) {
            u32 p = atomicAdd(&lcnt[og], 1u);
            lrows[og * 32 + p] = (ushort)(rg * 2 + rr);
        } else {
            // fused zero-fill of this inactive out slot (256 B)
            float4 zf = {0.f, 0.f, 0.f, 0.f};
            float4* o = reinterpret_cast<float4*>(
                &out[(size_t)row * (EEXP * LDIM) + og * LDIM]);
            #pragma unroll
            for (int i = 0; i < 16; ++i) o[i] = zf;
        }
    }

    __syncthreads();
    if (t < 16) lbase[t] = atomicAdd(&cnt[t], lcnt[t]);
    __syncthreads();
    for (int i = t; i < 16 * 32; i += 256) {
        int e = i >> 5, j = i & 31;
        if ((u32)j < lcnt[e])
            rowlist[(size_t)e * BROWS + lbase[e] + j] = row0 + lrows[e * 32 + j];
    }
}

// ---------------------------------------------------------------------------
// Sparse expert MLP, BM=128 (doubled row tile): B (W1T, 32 KB/step) staged
// ONCE per 128 rows instead of per 64 -> B staging traffic and LDS
// reads-per-FLOP drop (af reuse 4x, bfr reuse 8x). 4 waves, acc 8x4/wave.
// Phase B runs in two 64-row halves so h stays 32 KB. LDS 48 KB -> 3/CU.
// ---------------------------------------------------------------------------
__global__ __launch_bounds__(256, 2) void expert_kernel(
    const ushort* __restrict__ xbf,    // [B][D] bf16, swizzled
    const float*  __restrict__ gates,  // [B][E]
    const ushort* __restrict__ W1T,    // [E][H][D] bf16, swizzled
    const float*  __restrict__ b1,     // [E][H]
    const ushort* __restrict__ W2T,    // [E][L][H] bf16, linear
    const float*  __restrict__ b2,     // [E][L]
    const u32*    __restrict__ cnt,    // [E]
    const u32*    __restrict__ rowlist,// [E][B]
    float* __restrict__ out)           // [B][E][L]
{
    // A [0,8192) ushorts (128 rows x 64), B [8192,24576) (256 rows x 64).
    // h (per 64-row half) reuses [0,16384) after the K-loop.
    __shared__ __align__(16) ushort lds[24576];  // 48 KB

    const int bx = blockIdx.x;
    const int e  = bx & 15;
    const int t  = bx >> 4;

    const int count = (int)cnt[e];
    if (t * BM >= count) return;
    const int nrt = min(BM, count - t * BM);
    const u32* rl = rowlist + (size_t)e * BROWS + t * BM;

    const int tid  = threadIdx.x;
    const int lane = tid & 63;
    const int wave = tid >> 6;

    const int lr = lane & 15;
    const int q  = lane >> 4;
    const int kq = q * 8;
    const int rq = q * 4;
    const int la = lane >> 3, lb = lane & 7;  // staging lane split

    const char* xg = (const char*)xbf;
    const char* w1 = (const char*)W1T + (size_t)e * HDIM * 1024;

    // Per-lane gathered A-row bases + swizzle re-key terms (4 rows/lane)
    size_t abase[4]; int sxr[4];
    #pragma unroll
    for (int p = 0; p < 4; ++p) {
        int r  = wave * 32 + p * 8 + la;
        int rc = min(r, nrt - 1);
        u32 ri = rl[rc];
        abase[p] = (size_t)ri * 1024;
        sxr[p]   = (la ^ (int)(ri & 7)) << 4;
    }

    floatx4 acc[8][4] = {};

    for (int kb = 0; kb < 8; ++kb) {
        const int koff = kb * 128;   // byte offset within 1024-B row
        #pragma unroll
        for (int p = 0; p < 4; ++p) {   // A tile: 16 KB (128 gathered rows)
            int c = wave * 4 + p;
            gl_lds16(xg + abase[p] + koff + ((lb << 4) ^ sxr[p]), &lds[c * 512]);
        }
        #pragma unroll
        for (int p = 0; p < 8; ++p) {   // B tile: 32 KB (256 W1T rows)
            int c = wave * 8 + p;
            gl_lds16(w1 + (size_t)(c * 8 + la) * 1024 + koff + (lb << 4),
                     &lds[8192 + c * 512]);
        }
        __syncthreads();

        #pragma unroll
        for (int s = 0; s < 2; ++s) {
            const int g = s * 4 + q;
            bf16x8 af[8], bfr[4];
            #pragma unroll
            for (int i = 0; i < 8; ++i) {
                int r = i * 16 + lr;
                af[i] = *reinterpret_cast<const bf16x8*>(&lds[r * 64 + ((g ^ (r & 7)) << 3)]);
            }
            #pragma unroll
            for (int j = 0; j < 4; ++j) {
                int r = wave * 64 + j * 16 + lr;
                bfr[j] = *reinterpret_cast<const bf16x8*>(&lds[8192 + r * 64 + ((g ^ (r & 7)) << 3)]);
            }
            #pragma unroll
            for (int i = 0; i < 8; ++i)
                #pragma unroll
                for (int j = 0; j < 4; ++j)
                    acc[i][j] = __builtin_amdgcn_mfma_f32_16x16x32_bf16(
                        af[i], bfr[j], acc[i][j], 0, 0, 0);
        }
        __syncthreads();
    }

    float b1v[4];
    #pragma unroll
    for (int j = 0; j < 4; ++j)
        b1v[j] = b1[e * HDIM + wave * 64 + j * 16 + lr];
    float b2v[4];
    #pragma unroll
    for (int j = 0; j < 4; ++j)
        b2v[j] = b2[e * LDIM + j * 16 + lr];

    const ushort* w2 = W2T + (size_t)e * LDIM * HDIM;

    // Two 64-row halves: h = tanh(acc+b1) -> swizzled [64][256] bf16 in
    // lds[0,16384), then PV for those rows, then next half.
    #pragma unroll
    for (int hh = 0; hh < 2; ++hh) {
        #pragma unroll
        for (int i = 0; i < 4; ++i)
            #pragma unroll
            for (int j = 0; j < 4; ++j) {
                int c = wave * 64 + j * 16 + lr;
                int gg = c >> 3;
                #pragma unroll
                for (int rr = 0; rr < 4; ++rr) {
                    int r = i * 16 + rq + rr;   // local row within half
                    float v = fast_tanh(acc[hh * 4 + i][j][rr] + b1v[j]);
                    lds[r * 256 + (((gg & 24) | ((gg & 7) ^ (r & 7))) << 3) + (c & 7)] = f2bf(v);
                }
            }
        __syncthreads();

        floatx4 acc2[4] = {};
        #pragma unroll
        for (int s = 0; s < 8; ++s) {
            int r = wave * 16 + lr;
            int g = s * 4 + q;
            bf16x8 af = *reinterpret_cast<const bf16x8*>(
                &lds[r * 256 + (((g & 24) | ((g & 7) ^ (r & 7))) << 3)]);
            #pragma unroll
            for (int j = 0; j < 4; ++j) {
                bf16x8 bfr = *reinterpret_cast<const bf16x8*>(
                    &w2[(size_t)(j * 16 + lr) * HDIM + s * 32 + kq]);
                acc2[j] = __builtin_amdgcn_mfma_f32_16x16x32_bf16(af, bfr, acc2[j], 0, 0, 0);
            }
        }

        #pragma unroll
        for (int rr = 0; rr < 4; ++rr) {
            int r  = hh * 64 + wave * 16 + rq + rr;   // row within tile
            int rc = min(r, nrt - 1);
            u32 ri = rl[rc];
            float gsc = gates[(size_t)ri * EEXP + e];
            if (r < nrt) {
                #pragma unroll
                for (int j = 0; j < 4; ++j)
                    out[(size_t)ri * (EEXP * LDIM) + e * LDIM + j * 16 + lr] =
                        (acc2[j][rr] + b2v[j]) * gsc;
            }
        }
        __syncthreads();   // protect h before next half overwrites
    }
}

// ---------------------------------------------------------------------------
extern "C" void kernel_launch(void* const* d_in, const int* in_sizes, int n_in,
                              void* d_out, int out_size, void* d_ws, size_t ws_size,
                              hipStream_t stream) {
    (void)in_sizes; (void)n_in; (void)out_size; (void)ws_size;
    const float* x     = (const float*)d_in[0];
    const float* noise = (const float*)d_in[1];
    const float* wg    = (const float*)d_in[2];
    const float* wn    = (const float*)d_in[3];
    const float* W1    = (const float*)d_in[4];
    const float* b1    = (const float*)d_in[5];
    const float* W2    = (const float*)d_in[6];
    const float* b2    = (const float*)d_in[7];
    float* out = (float*)d_out;

    char* ws = (char*)d_ws;
    float*  gates   = (float*)ws;                          // 1 MiB
    ushort* W1T     = (ushort*)(ws + (1 << 20));           // 4 MiB
    ushort* W2T     = (ushort*)(ws + (5 << 20));           // 0.5 MiB
    ushort* xbf     = (ushort*)(ws + (6 << 20));           // 16 MiB
    u32*    cnt     = (u32*)(ws + (22 << 20));             // 64 B
    u32*    rowlist = (u32*)(ws + (24 << 20));             // 1 MiB

    hipMemsetAsync(cnt, 0, EEXP * sizeof(u32), stream);
    gate_aux_kernel<<<512 + 2304, 256, 0, stream>>>(
        x, noise, wg, wn, W1, W2, gates, xbf, W1T, W2T, cnt, rowlist, out);
    expert_kernel<<<(BROWS / BM) * EEXP, 256, 0, stream>>>(
        xbf, gates, W1T, b1, W2T, b2, cnt, rowlist, out);
}